// Round 1
// baseline (1685.948 us; speedup 1.0000x reference)
//
#include <hip/hip_runtime.h>

#define TT 1024
#define BB 2048
#define EPSC 1e-4f

// ---------------------------------------------------------------------------
// Phase 1: sequential Riccati / gain recursion (batch-independent!).
// One wave (64 lanes). Lane l: r = l&15 (row), q = l>>4 (column quarter).
// Lane owns P[r][4q..4q+3]. Writes per step: A_t[16][16], GT_t[16][4]
// where A_t = F - Kt^T (H F), GT_t[i][m] = Kt[m][i].
// ---------------------------------------------------------------------------
__global__ __launch_bounds__(64, 1)
void ssm_gains(const float* __restrict__ F, const float* __restrict__ H,
               const float* __restrict__ Qc, const float* __restrict__ Rc,
               const float* __restrict__ icc,
               float* __restrict__ A_g, float* __restrict__ GT_g)
{
    const int l = (int)threadIdx.x;
    const int r = l & 15;
    const int q = l >> 4;

    __shared__ __align__(16) float m1[256];
    __shared__ __align__(16) float m2[256];
    __shared__ __align__(16) float hptl[64];
    __shared__ __align__(16) float Sl[16];

    // Loop-invariant operands in registers (single wave -> huge VGPR budget).
    float Fq[4][16];   // F[4q+i][k]
    float Fr[16];      // F[r][k]
    float Hq[16];      // H[q][k]
    float Frq[4];      // F[r][4q+i]
    float Hr[4];       // H[n][r]
    float HFq[4][4];   // (H F)[m][4q+i]
    float Qq[4];       // Q[r][4q+i]
    float Rrow[4];     // R[q][n]
    float p[4];        // state: P[r][4q+i]

    #pragma unroll
    for (int i = 0; i < 4; ++i)
        #pragma unroll
        for (int k = 0; k < 16; ++k)
            Fq[i][k] = F[(4*q + i)*16 + k];
    #pragma unroll
    for (int k = 0; k < 16; ++k) Fr[k] = F[r*16 + k];
    #pragma unroll
    for (int i = 0; i < 4; ++i) Frq[i] = F[r*16 + 4*q + i];
    #pragma unroll
    for (int k = 0; k < 16; ++k) Hq[k] = H[q*16 + k];
    #pragma unroll
    for (int n = 0; n < 4; ++n) Hr[n] = H[n*16 + r];
    #pragma unroll
    for (int m = 0; m < 4; ++m)
        #pragma unroll
        for (int i = 0; i < 4; ++i) {
            float acc = 0.0f;
            #pragma unroll
            for (int k = 0; k < 16; ++k) acc += H[m*16 + k] * F[k*16 + 4*q + i];
            HFq[m][i] = acc;
        }
    #pragma unroll
    for (int i = 0; i < 4; ++i) {
        const int c = 4*q + i;
        float accq = (r == c) ? EPSC : 0.0f;
        float accp = (r == c) ? EPSC : 0.0f;
        #pragma unroll
        for (int k = 0; k < 16; ++k) {
            accq += Qc[r*16 + k]  * Qc[c*16 + k];
            accp += icc[r*16 + k] * icc[c*16 + k];
        }
        Qq[i] = accq;
        p[i]  = accp;    // P0 = icc icc^T + eps I (exactly symmetric)
    }
    #pragma unroll
    for (int n = 0; n < 4; ++n) {
        float acc = (q == n) ? EPSC : 0.0f;
        #pragma unroll
        for (int k = 0; k < 4; ++k) acc += Rc[q*4 + k] * Rc[n*4 + k];
        Rrow[n] = acc;
    }

    #pragma unroll 1
    for (int t = 0; t < TT; ++t) {
        // ---- gather full P row r ----
        *(float4*)&m1[r*16 + 4*q] = make_float4(p[0], p[1], p[2], p[3]);
        __syncthreads();
        float prow[16];
        #pragma unroll
        for (int j = 0; j < 4; ++j) {
            float4 v = *(const float4*)&m1[r*16 + 4*j];
            prow[4*j+0] = v.x; prow[4*j+1] = v.y; prow[4*j+2] = v.z; prow[4*j+3] = v.w;
        }
        // ---- C = P F^T (lane computes C[r][4q+i]) ----
        float c[4];
        #pragma unroll
        for (int i = 0; i < 4; ++i) {
            float acc = 0.0f;
            #pragma unroll
            for (int k = 0; k < 16; ++k) acc += prow[k] * Fq[i][k];
            c[i] = acc;
        }
        // ---- cov_p = F C + Q (needs columns of C -> via LDS) ----
        __syncthreads();
        *(float4*)&m2[r*16 + 4*q] = make_float4(c[0], c[1], c[2], c[3]);
        __syncthreads();
        float cp[4] = {Qq[0], Qq[1], Qq[2], Qq[3]};
        #pragma unroll
        for (int k = 0; k < 16; ++k) {
            float4 ck = *(const float4*)&m2[k*16 + 4*q];
            cp[0] += Fr[k]*ck.x; cp[1] += Fr[k]*ck.y;
            cp[2] += Fr[k]*ck.z; cp[3] += Fr[k]*ck.w;
        }
        // ---- gather full cov_p row ----
        __syncthreads();
        *(float4*)&m1[r*16 + 4*q] = make_float4(cp[0], cp[1], cp[2], cp[3]);
        __syncthreads();
        float cprow[16];
        #pragma unroll
        for (int j = 0; j < 4; ++j) {
            float4 v = *(const float4*)&m1[r*16 + 4*j];
            cprow[4*j+0] = v.x; cprow[4*j+1] = v.y; cprow[4*j+2] = v.z; cprow[4*j+3] = v.w;
        }
        // ---- HPT[r][q] = (cov_p H^T)[r][q]  (= HP[q][r], cov_p symmetric) ----
        float hpt = 0.0f;
        #pragma unroll
        for (int k = 0; k < 16; ++k) hpt += cprow[k] * Hq[k];
        // ---- S[q][n] = sum_r HPT[r][q] H[n][r] + R[q][n] : reduce over r ----
        float sv[4];
        #pragma unroll
        for (int n = 0; n < 4; ++n) sv[n] = hpt * Hr[n];
        #pragma unroll
        for (int d = 1; d < 16; d <<= 1) {
            #pragma unroll
            for (int n = 0; n < 4; ++n) sv[n] += __shfl_xor(sv[n], d);
        }
        #pragma unroll
        for (int n = 0; n < 4; ++n) sv[n] += Rrow[n];
        hptl[r*4 + q] = hpt;
        if (r == 0) *(float4*)&Sl[q*4] = make_float4(sv[0], sv[1], sv[2], sv[3]);
        __syncthreads();
        float sf[16];
        #pragma unroll
        for (int j = 0; j < 4; ++j) {
            float4 v = *(const float4*)&Sl[4*j];
            sf[4*j+0] = v.x; sf[4*j+1] = v.y; sf[4*j+2] = v.z; sf[4*j+3] = v.w;
        }
        float4 rhs4 = *(const float4*)&hptl[r*4];   // HP[:, r]

        // ---- solve S x = rhs (4x4 SPD, symmetric Gaussian elim, no pivot) ----
        float b0 = rhs4.x, b1 = rhs4.y, b2 = rhs4.z, b3 = rhs4.w;
        float a00 = sf[0],  a01 = sf[1],  a02 = sf[2],  a03 = sf[3];
        float a11 = sf[5],  a12 = sf[6],  a13 = sf[7];
        float a22 = sf[10], a23 = sf[11];
        float a33 = sf[15];
        float i0 = 1.0f / a00;
        float g1 = a01*i0, g2 = a02*i0, g3 = a03*i0;
        a11 -= g1*a01; a12 -= g1*a02; a13 -= g1*a03;
        a22 -= g2*a02; a23 -= g2*a03;
        a33 -= g3*a03;
        b1 -= g1*b0; b2 -= g2*b0; b3 -= g3*b0;
        float i1 = 1.0f / a11;
        float h2 = a12*i1, h3 = a13*i1;
        a22 -= h2*a12; a23 -= h2*a13;
        a33 -= h3*a13;
        b2 -= h2*b1; b3 -= h3*b1;
        float i2 = 1.0f / a22;
        float w3 = a23*i2;
        a33 -= w3*a23;
        b3 -= w3*b2;
        float x3 = b3 / a33;
        float x2 = (b2 - a23*x3) * i2;
        float x1 = (b1 - a12*x2 - a13*x3) * i1;
        float x0 = (b0 - a01*x1 - a02*x2 - a03*x3) * i0;
        // kcol[m] = Kt[m][r]
        float kc0 = x0, kc1 = x1, kc2 = x2, kc3 = x3;

        // ---- A_t[r][4q+i] = F - Kt^T (H F) ; store ----
        float av[4];
        #pragma unroll
        for (int i = 0; i < 4; ++i)
            av[i] = Frq[i] - (kc0*HFq[0][i] + kc1*HFq[1][i] + kc2*HFq[2][i] + kc3*HFq[3][i]);
        *(float4*)&A_g[t*256 + r*16 + 4*q] = make_float4(av[0], av[1], av[2], av[3]);
        if (q == 0)
            *(float4*)&GT_g[t*64 + r*4] = make_float4(kc0, kc1, kc2, kc3);

        // ---- cov_u[r][c] = cov_p[r][c] - sum_m Kt[m][r] HPT[c][m] ----
        float cu[4];
        #pragma unroll
        for (int i = 0; i < 4; ++i) {
            float4 hrow = *(const float4*)&hptl[(4*q + i)*4];
            cu[i] = cp[i] - (kc0*hrow.x + kc1*hrow.y + kc2*hrow.z + kc3*hrow.w);
        }
        // ---- symmetrize: P = 0.5 (cov_u + cov_u^T) ----
        __syncthreads();
        *(float4*)&m2[r*16 + 4*q] = make_float4(cu[0], cu[1], cu[2], cu[3]);
        __syncthreads();
        #pragma unroll
        for (int i = 0; i < 4; ++i)
            p[i] = 0.5f * (cu[i] + m2[(4*q + i)*16 + r]);
        __syncthreads();
    }
}

// ---------------------------------------------------------------------------
// Phase 2: per-batch mean recurrence  mean_t = A_t mean_{t-1} + GT_t y_t.
// 16 lanes per batch (lane i computes mean[i]); 16 batches per 256-thr block.
// ---------------------------------------------------------------------------
__global__ __launch_bounds__(256)
void ssm_means(const float* __restrict__ y, const float* __restrict__ im,
               const float* __restrict__ A_g, const float* __restrict__ GT_g,
               float* __restrict__ out)
{
    const int tid = (int)threadIdx.x;
    const int g = tid >> 4;          // batch-local group 0..15
    const int i = tid & 15;          // state row
    const int b = (int)blockIdx.x * 16 + g;

    __shared__ __align__(16) float msh[16][16];

    float mean[16];
    #pragma unroll
    for (int k = 0; k < 16; ++k) mean[k] = im[k];

    const float4* A4 = (const float4*)A_g;   // A4[t*64 + i*4 + j]
    const float4* G4 = (const float4*)GT_g;  // G4[t*16 + i]
    const float4* Y4 = (const float4*)y + (size_t)b * TT;
    float* outb = out + ((size_t)b * TT) * 16 + i;

    float4 a0 = A4[i*4 + 0], a1 = A4[i*4 + 1], a2 = A4[i*4 + 2], a3 = A4[i*4 + 3];
    float4 gt = G4[i];
    float4 yv = Y4[0];

    #pragma unroll 1
    for (int t = 0; t < TT; ++t) {
        // prefetch next step's operands (addresses are data-independent)
        float4 na0, na1, na2, na3, ngt, nyv;
        if (t + 1 < TT) {
            const float4* An = A4 + (size_t)(t + 1)*64 + i*4;
            na0 = An[0]; na1 = An[1]; na2 = An[2]; na3 = An[3];
            ngt = G4[(t + 1)*16 + i];
            nyv = Y4[t + 1];
        }
        float nm = a0.x*mean[0]  + a0.y*mean[1]  + a0.z*mean[2]  + a0.w*mean[3]
                 + a1.x*mean[4]  + a1.y*mean[5]  + a1.z*mean[6]  + a1.w*mean[7]
                 + a2.x*mean[8]  + a2.y*mean[9]  + a2.z*mean[10] + a2.w*mean[11]
                 + a3.x*mean[12] + a3.y*mean[13] + a3.z*mean[14] + a3.w*mean[15]
                 + gt.x*yv.x + gt.y*yv.y + gt.z*yv.z + gt.w*yv.w;
        outb[(size_t)t * 16] = nm;

        // rebuild replicated mean via group-private LDS (single-wave group,
        // per-wave in-order LDS: no barrier needed)
        msh[g][i] = nm;
        __builtin_amdgcn_wave_barrier();
        #pragma unroll
        for (int j = 0; j < 4; ++j) {
            float4 v = *(const float4*)&msh[g][4*j];
            mean[4*j+0] = v.x; mean[4*j+1] = v.y; mean[4*j+2] = v.z; mean[4*j+3] = v.w;
        }
        if (t + 1 < TT) { a0 = na0; a1 = na1; a2 = na2; a3 = na3; gt = ngt; yv = nyv; }
    }
}

extern "C" void kernel_launch(void* const* d_in, const int* in_sizes, int n_in,
                              void* d_out, int out_size, void* d_ws, size_t ws_size,
                              hipStream_t stream)
{
    const float* y   = (const float*)d_in[0];
    const float* F   = (const float*)d_in[1];
    const float* H   = (const float*)d_in[2];
    const float* Qc  = (const float*)d_in[3];
    const float* Rc  = (const float*)d_in[4];
    const float* im  = (const float*)d_in[5];
    const float* icc = (const float*)d_in[6];
    float* out = (float*)d_out;

    float* A_g  = (float*)d_ws;           // TT*256 floats
    float* GT_g = A_g + TT * 256;         // TT*64 floats

    ssm_gains<<<dim3(1), dim3(64), 0, stream>>>(F, H, Qc, Rc, icc, A_g, GT_g);
    ssm_means<<<dim3(BB/16), dim3(256), 0, stream>>>(y, im, A_g, GT_g, out);
}

// Round 4
// 1279.912 us; speedup vs baseline: 1.3172x; 1.3172x over previous
//
#include <hip/hip_runtime.h>

#define TT 1024
#define BB 2048
#define EPSC 1e-4f
#define LDP 20   // padded LDS row stride (floats): 20r+4j mod 32 -> max 2-way (free)

// Fused Kalman filter. Grid 256 x 192 threads (3 waves).
// wave 0: redundant (batch-independent) Riccati/gain recursion, pure
//         wave-synchronous LDS (NO barriers inside the chain, no global stores).
// waves 1-2: 8 batches of the mean recurrence, one step behind, reading
//         A_t/G_t from double-buffered LDS. One uniform __syncthreads per step.
__global__ __launch_bounds__(192, 1)
void ssm_fused(const float* __restrict__ y, const float* __restrict__ F,
               const float* __restrict__ H, const float* __restrict__ Qc,
               const float* __restrict__ Rc, const float* __restrict__ im,
               const float* __restrict__ icc, float* __restrict__ out)
{
    __shared__ __align__(16) float m1[16 * LDP];
    __shared__ __align__(16) float m2[16 * LDP];
    __shared__ __align__(16) float A_l[2][16 * LDP];
    __shared__ __align__(16) float G_l[2][64];
    __shared__ __align__(16) float msh[2][4][16];

    const int tid = (int)threadIdx.x;
    const int wv  = tid >> 6;
    const int l   = tid & 63;
    const int r   = l & 15;
    const int q   = l >> 4;

    // ---- gains-wave loop-invariant registers ----
    float Fq[4][16];   // F[4q+i][k]
    float Fr[16];      // F[r][k]
    float Frq[4];      // F[r][4q+i]
    float HFq[4][4];   // (H F)[m][4q+i]
    float Hn4q[4][4];  // H[n][4q+i]
    float Qq[4];       // Q[r][4q+i]
    float Rrow[4];     // R[q][n]
    float Hqr = 0.0f;  // H[q][r]
    float prow[16];    // state: full row r of symmetric P (replicated over q)

    // ---- means-wave registers ----
    float mean[16];
    const float4* Y4 = nullptr;
    float* outb = nullptr;

    if (wv == 0) {
        #pragma unroll
        for (int i = 0; i < 4; ++i)
            #pragma unroll
            for (int k = 0; k < 16; ++k) Fq[i][k] = F[(4*q + i)*16 + k];
        #pragma unroll
        for (int k = 0; k < 16; ++k) Fr[k] = F[r*16 + k];
        #pragma unroll
        for (int i = 0; i < 4; ++i) Frq[i] = F[r*16 + 4*q + i];
        #pragma unroll
        for (int n = 0; n < 4; ++n)
            #pragma unroll
            for (int i = 0; i < 4; ++i) Hn4q[n][i] = H[n*16 + 4*q + i];
        Hqr = H[q*16 + r];
        #pragma unroll
        for (int m = 0; m < 4; ++m)
            #pragma unroll
            for (int i = 0; i < 4; ++i) {
                float acc = 0.0f;
                #pragma unroll
                for (int k = 0; k < 16; ++k) acc += H[m*16 + k] * F[k*16 + 4*q + i];
                HFq[m][i] = acc;
            }
        #pragma unroll
        for (int i = 0; i < 4; ++i) {
            const int c = 4*q + i;
            float acc = (r == c) ? EPSC : 0.0f;
            #pragma unroll
            for (int k = 0; k < 16; ++k) acc += Qc[r*16 + k] * Qc[c*16 + k];
            Qq[i] = acc;
        }
        #pragma unroll
        for (int n = 0; n < 4; ++n) {
            float acc = (q == n) ? EPSC : 0.0f;
            #pragma unroll
            for (int k = 0; k < 4; ++k) acc += Rc[q*4 + k] * Rc[n*4 + k];
            Rrow[n] = acc;
        }
        #pragma unroll
        for (int k = 0; k < 16; ++k) {
            float acc = (r == k) ? EPSC : 0.0f;
            #pragma unroll
            for (int j = 0; j < 16; ++j) acc += icc[r*16 + j] * icc[k*16 + j];
            prow[k] = acc;   // P0 row r (exactly symmetric by construction)
        }
    } else {
        const int g = (tid >> 4) & 3;
        const int i16 = tid & 15;
        const int b = (int)blockIdx.x * 8 + (wv - 1) * 4 + g;
        #pragma unroll
        for (int k = 0; k < 16; ++k) mean[k] = im[k];
        Y4 = (const float4*)y + (size_t)b * TT;
        outb = out + ((size_t)b * TT) * 16 + i16;
    }

    #pragma unroll 1
    for (int t = 0; t <= TT; ++t) {
        if (wv == 0 && t < TT) {
            // ================= gains step t (single wave, no barriers) =====
            // C[r][4q+i] = sum_k P[r][k] F[4q+i][k]
            float c0 = 0.f, c1 = 0.f, c2 = 0.f, c3 = 0.f;
            #pragma unroll
            for (int k = 0; k < 16; ++k) {
                c0 += prow[k]*Fq[0][k]; c1 += prow[k]*Fq[1][k];
                c2 += prow[k]*Fq[2][k]; c3 += prow[k]*Fq[3][k];
            }
            // RT_A: transpose C through LDS, cov_p = F C + Q
            *(float4*)&m2[r*LDP + 4*q] = make_float4(c0, c1, c2, c3);
            __builtin_amdgcn_wave_barrier();
            float cp[4] = {Qq[0], Qq[1], Qq[2], Qq[3]};
            #pragma unroll
            for (int k = 0; k < 16; ++k) {
                float4 ck = *(const float4*)&m2[k*LDP + 4*q];
                cp[0] += Fr[k]*ck.x; cp[1] += Fr[k]*ck.y;
                cp[2] += Fr[k]*ck.z; cp[3] += Fr[k]*ck.w;
            }
            __builtin_amdgcn_wave_barrier();
            // HPT[r][n] = sum_k cov_p[r][k] H[n][k]: quarter partials + q-reduce
            float hv[4];
            #pragma unroll
            for (int n = 0; n < 4; ++n) {
                float s = cp[0]*Hn4q[n][0] + cp[1]*Hn4q[n][1]
                        + cp[2]*Hn4q[n][2] + cp[3]*Hn4q[n][3];
                s += __shfl_xor(s, 16);
                s += __shfl_xor(s, 32);
                hv[n] = s;                      // replicated over q
            }
            // S[q][n] = sum_r H[q][r] HPT[r][n] + R[q][n]  (reduce over r)
            float sm[4];
            #pragma unroll
            for (int n = 0; n < 4; ++n) sm[n] = Hqr * hv[n];
            #pragma unroll
            for (int d = 1; d < 16; d <<= 1) {
                #pragma unroll
                for (int n = 0; n < 4; ++n) sm[n] += __shfl_xor(sm[n], d);
            }
            #pragma unroll
            for (int n = 0; n < 4; ++n) sm[n] += Rrow[n];
            // gather full S into every lane
            float sf[16];
            #pragma unroll
            for (int j = 0; j < 4; ++j)
                #pragma unroll
                for (int n = 0; n < 4; ++n)
                    sf[4*j + n] = __shfl(sm[n], (j << 4) | r);
            // solve S x = HP[:,r]  (rhs[m] = HPT[r][m] = hv[m])
            float b0 = hv[0], b1 = hv[1], b2 = hv[2], b3 = hv[3];
            float a00 = sf[0],  a01 = sf[1],  a02 = sf[2],  a03 = sf[3];
            float a11 = sf[5],  a12 = sf[6],  a13 = sf[7];
            float a22 = sf[10], a23 = sf[11];
            float a33 = sf[15];
            float i0 = 1.0f / a00;
            float g1 = a01*i0, g2 = a02*i0, g3 = a03*i0;
            a11 -= g1*a01; a12 -= g1*a02; a13 -= g1*a03;
            a22 -= g2*a02; a23 -= g2*a03;
            a33 -= g3*a03;
            b1 -= g1*b0; b2 -= g2*b0; b3 -= g3*b0;
            float i1 = 1.0f / a11;
            float h2 = a12*i1, h3 = a13*i1;
            a22 -= h2*a12; a23 -= h2*a13;
            a33 -= h3*a13;
            b2 -= h2*b1; b3 -= h3*b1;
            float i2 = 1.0f / a22;
            float w3 = a23*i2;
            a33 -= w3*a23;
            b3 -= w3*b2;
            float x3 = b3 / a33;
            float x2 = (b2 - a23*x3) * i2;
            float x1 = (b1 - a12*x2 - a13*x3) * i1;
            float x0 = (b0 - a01*x1 - a02*x2 - a03*x3) * i0;
            // A_t row -> LDS double buffer
            const int buf = t & 1;
            float av[4];
            #pragma unroll
            for (int i = 0; i < 4; ++i)
                av[i] = Frq[i] - (x0*HFq[0][i] + x1*HFq[1][i] + x2*HFq[2][i] + x3*HFq[3][i]);
            *(float4*)&A_l[buf][r*LDP + 4*q] = make_float4(av[0], av[1], av[2], av[3]);
            if (q == 0)
                *(float4*)&G_l[buf][r*4] = make_float4(x0, x1, x2, x3);
            // cov_u[r][4q+i] = cov_p - sum_m K[m][r] HPT[4q+i][m]
            float cu[4];
            #pragma unroll
            for (int i = 0; i < 4; ++i) {
                float h0 = __shfl(hv[0], (l & 48) | (4*q + i));
                float h1 = __shfl(hv[1], (l & 48) | (4*q + i));
                float h2s = __shfl(hv[2], (l & 48) | (4*q + i));
                float h3s = __shfl(hv[3], (l & 48) | (4*q + i));
                cu[i] = cp[i] - (x0*h0 + x1*h1 + x2*h2s + x3*h3s);
            }
            // RT_B: symmetrize and rebuild the full replicated row
            *(float4*)&m1[r*LDP + 4*q] = make_float4(cu[0], cu[1], cu[2], cu[3]);
            #pragma unroll
            for (int i = 0; i < 4; ++i) m2[(4*q + i)*LDP + r] = cu[i];
            __builtin_amdgcn_wave_barrier();
            #pragma unroll
            for (int j = 0; j < 4; ++j) {
                float4 va = *(const float4*)&m1[r*LDP + 4*j];
                float4 vb = *(const float4*)&m2[r*LDP + 4*j];
                prow[4*j+0] = 0.5f*(va.x + vb.x);
                prow[4*j+1] = 0.5f*(va.y + vb.y);
                prow[4*j+2] = 0.5f*(va.z + vb.z);
                prow[4*j+3] = 0.5f*(va.w + vb.w);
            }
            __builtin_amdgcn_wave_barrier();
        }
        if (wv > 0 && t > 0) {
            // ================= means step u = t-1 for 4 batches ============
            const int u   = t - 1;
            const int buf = u & 1;
            const int g   = (tid >> 4) & 3;
            const int i16 = tid & 15;
            const int widx = wv - 1;
            float4 yv = Y4[u];
            float4 gt = *(const float4*)&G_l[buf][i16*4];
            float4 a0 = *(const float4*)&A_l[buf][i16*LDP + 0];
            float4 a1 = *(const float4*)&A_l[buf][i16*LDP + 4];
            float4 a2 = *(const float4*)&A_l[buf][i16*LDP + 8];
            float4 a3 = *(const float4*)&A_l[buf][i16*LDP + 12];
            float nm = a0.x*mean[0]  + a0.y*mean[1]  + a0.z*mean[2]  + a0.w*mean[3]
                     + a1.x*mean[4]  + a1.y*mean[5]  + a1.z*mean[6]  + a1.w*mean[7]
                     + a2.x*mean[8]  + a2.y*mean[9]  + a2.z*mean[10] + a2.w*mean[11]
                     + a3.x*mean[12] + a3.y*mean[13] + a3.z*mean[14] + a3.w*mean[15]
                     + gt.x*yv.x + gt.y*yv.y + gt.z*yv.z + gt.w*yv.w;
            outb[(size_t)u * 16] = nm;
            msh[widx][g][i16] = nm;
            __builtin_amdgcn_wave_barrier();
            #pragma unroll
            for (int j = 0; j < 4; ++j) {
                float4 v = *(const float4*)&msh[widx][g][4*j];
                mean[4*j+0] = v.x; mean[4*j+1] = v.y;
                mean[4*j+2] = v.z; mean[4*j+3] = v.w;
            }
            __builtin_amdgcn_wave_barrier();
        }
        __syncthreads();
    }
}

extern "C" void kernel_launch(void* const* d_in, const int* in_sizes, int n_in,
                              void* d_out, int out_size, void* d_ws, size_t ws_size,
                              hipStream_t stream)
{
    const float* y   = (const float*)d_in[0];
    const float* F   = (const float*)d_in[1];
    const float* H   = (const float*)d_in[2];
    const float* Qc  = (const float*)d_in[3];
    const float* Rc  = (const float*)d_in[4];
    const float* im  = (const float*)d_in[5];
    const float* icc = (const float*)d_in[6];
    float* out = (float*)d_out;

    ssm_fused<<<dim3(BB/8), dim3(192), 0, stream>>>(y, F, H, Qc, Rc, im, icc, out);
}